// Round 12
// baseline (660.309 us; speedup 1.0000x reference)
//
#include <hip/hip_runtime.h>

// ---------------------------------------------------------------------------
// PoetryModel: embed -> x_gates GEMM -> LSTM(128 steps) -> classifier GEMM
//              -> log_softmax over V -> out (B, V, S) f32
// B=64 S=128 V=8000 E=256 H=512 G=4H=2048
// ---------------------------------------------------------------------------

using u16   = unsigned short;
using u32   = unsigned int;
using u16x4 = __attribute__((ext_vector_type(4))) u16;
using u16x8 = __attribute__((ext_vector_type(8))) u16;
using bf16x8 = __attribute__((ext_vector_type(8))) __bf16;
using f32x4 = __attribute__((ext_vector_type(4))) float;

#define NB   64        // batch
#define NS   128       // seq len
#define NV   8000      // vocab
#define NVP  8192      // vocab padded to tile
#define NE   256       // embed dim
#define NH   512       // hidden
#define NG   2048      // 4*H
#define NBS  8192      // B*S
#define OUT_BSTRIDE 1024000   // V*S
#define XG_SSTRIDE  131072    // G*B

__device__ inline u16 f2bf(float f) {
    unsigned x = __builtin_bit_cast(unsigned, f);
    unsigned r = (x + 0x7FFFu + ((x >> 16) & 1u)) >> 16;
    return (u16)r;
}
__device__ inline float bf2f(u16 x) {
    u32 u = ((u32)x) << 16;
    return __builtin_bit_cast(float, u);
}

__device__ inline bf16x8 ld_frag(const u16* p) {
    u16x8 v = *(const u16x8*)p;
    return __builtin_bit_cast(bf16x8, v);
}

// LLC-coherent ops: bypass L1+L2, never create/consume dirty L2 lines.
__device__ inline u32 load_llc(const u32* p) {
    u32 v;
    asm volatile("global_load_dword %0, %1, off sc0 sc1\n\t"
                 "s_waitcnt vmcnt(0)"
                 : "=v"(v) : "v"(p) : "memory");
    return v;
}
__device__ inline f32x4 load_llc16(const void* p) {
    f32x4 v;
    asm volatile("global_load_dwordx4 %0, %1, off sc0 sc1\n\t"
                 "s_waitcnt vmcnt(0)"
                 : "=v"(v) : "v"(p) : "memory");
    return v;
}
__device__ inline void store_llc(u32* p, u32 v) {
    asm volatile("global_store_dword %0, %1, off sc0 sc1"
                 :: "v"(p), "v"(v) : "memory");
}
__device__ inline void store_llc16(void* p, u16x8 v) {
    asm volatile("global_store_dwordx4 %0, %1, off sc0 sc1"
                 :: "v"(p), "v"(__builtin_bit_cast(f32x4, v)) : "memory");
}
// plain cached load, NO waitcnt: covered by a later vmcnt(0) before use
__device__ inline void prefetch16(f32x4& d, const float* p) {
    asm volatile("global_load_dwordx4 %0, %1, off"
                 : "=v"(d) : "v"(p) : "memory");
}

// direct global->LDS copy, 16B per lane (dst must be wave-uniform base)
__device__ inline void gload_lds16(const u16* g, u16* l) {
    __builtin_amdgcn_global_load_lds(
        (const __attribute__((address_space(1))) unsigned int*)(const void*)g,
        (__attribute__((address_space(3))) unsigned int*)(void*)l,
        16, 0, 0);
}

// 4x4 transpose across lane quad {p} x element {r} (verified round 3)
__device__ inline void quad_transpose(float v[4], int p) {
    float tb[4];
    #pragma unroll
    for (int q2 = 0; q2 < 4; ++q2) tb[q2] = __shfl_xor(v[q2 ^ 2], 2);
    #pragma unroll
    for (int q2 = 0; q2 < 4; ++q2) v[q2] = (((q2 ^ p) & 2) ? tb[q2] : v[q2]);
    #pragma unroll
    for (int q2 = 0; q2 < 4; ++q2) tb[q2] = __shfl_xor(v[q2 ^ 1], 1);
    #pragma unroll
    for (int q2 = 0; q2 < 4; ++q2) v[q2] = (((q2 ^ p) & 1) ? tb[q2] : v[q2]);
}

__device__ inline float lstm_cell(const float v[4], float& c) {
    float i_ = 1.f / (1.f + __expf(-v[0]));
    float f_ = 1.f / (1.f + __expf(-v[1]));
    float e2 = __expf(2.f * v[2]);
    float g_ = 1.f - 2.f / (e2 + 1.f);
    float o_ = 1.f / (1.f + __expf(-v[3]));
    c = f_ * c + i_ * g_;
    float e2c = __expf(2.f * c);
    return o_ * (1.f - 2.f / (e2c + 1.f));
}

// ------------------------------------------------- merged weight converts
__global__ void cvt_all(const float* __restrict__ e,  const float* __restrict__ wi,
                        const float* __restrict__ wh, const float* __restrict__ wc,
                        u16* __restrict__ de,  u16* __restrict__ dwi,
                        u16* __restrict__ dwh, u16* __restrict__ dwc) {
    const int N0 = NV * NE / 8, N1 = NG * NE / 8, N2 = NG * NH / 8, N3 = NV * NH / 8;
    const int total = N0 + N1 + N2 + N3;
    for (int i = blockIdx.x * blockDim.x + threadIdx.x; i < total;
         i += gridDim.x * blockDim.x) {
        const float* s; u16* d; int j;
        if (i < N0)                { s = e;  d = de;  j = i; }
        else if (i < N0 + N1)      { s = wi; d = dwi; j = i - N0; }
        else if (i < N0 + N1 + N2) { s = wh; d = dwh; j = i - N0 - N1; }
        else                       { s = wc; d = dwc; j = i - N0 - N1 - N2; }
        const float4* s4 = (const float4*)s;
        float4 a = s4[2 * j], b = s4[2 * j + 1];
        u16x8 o;
        o[0] = f2bf(a.x); o[1] = f2bf(a.y); o[2] = f2bf(a.z); o[3] = f2bf(a.w);
        o[4] = f2bf(b.x); o[5] = f2bf(b.y); o[6] = f2bf(b.z); o[7] = f2bf(b.w);
        ((u16x8*)d)[j] = o;
    }
}

// ------------------------------------------------- K1: x_gates = x @ W_ih^T
__global__ __launch_bounds__(256) void k1_xgates(
    const u16* __restrict__ Wih, const u16* __restrict__ emb,
    const int* __restrict__ toks,
    const float* __restrict__ bih, const float* __restrict__ bhh,
    float* __restrict__ xg)
{
    __shared__ u16x8 Al8[512];   // [128][32] bf16
    __shared__ u16x8 Bl8[512];
    u16* Al = (u16*)Al8;
    u16* Bl = (u16*)Bl8;

    const int t = threadIdx.x;
    const int lane = t & 63, w = t >> 6;
    const int wm = w >> 1, wn = w & 1;
    const int gtile = blockIdx.y * 128, mtile = blockIdx.x * 128;

    const int r0 = t >> 2, r1 = r0 + 64, q = t & 3;
    const int m0 = mtile + r0, m1 = mtile + r1;
    const int tok0 = toks[(m0 & 63) * NS + (m0 >> 6)];
    const int tok1 = toks[(m1 & 63) * NS + (m1 >> 6)];

    f32x4 acc[4][4];
    for (int i = 0; i < 4; ++i)
        for (int j = 0; j < 4; ++j) acc[i][j] = {0.f, 0.f, 0.f, 0.f};

    const int kc8 = (lane >> 4) * 8;
    for (int kk = 0; kk < 8; ++kk) {
        const int k0 = kk * 32;
        *(u16x8*)&Al[t * 8]         = *(const u16x8*)&Wih[(gtile + r0) * NE + k0 + q * 8];
        *(u16x8*)&Al[(t + 256) * 8] = *(const u16x8*)&Wih[(gtile + r1) * NE + k0 + q * 8];
        *(u16x8*)&Bl[t * 8]         = *(const u16x8*)&emb[tok0 * NE + k0 + q * 8];
        *(u16x8*)&Bl[(t + 256) * 8] = *(const u16x8*)&emb[tok1 * NE + k0 + q * 8];
        __syncthreads();
        bf16x8 af[4], bf[4];
        #pragma unroll
        for (int i = 0; i < 4; ++i) {
            af[i] = ld_frag(&Al[(wm * 64 + i * 16 + (lane & 15)) * 32 + kc8]);
            bf[i] = ld_frag(&Bl[(wn * 64 + i * 16 + (lane & 15)) * 32 + kc8]);
        }
        #pragma unroll
        for (int fi = 0; fi < 4; ++fi)
            #pragma unroll
            for (int fj = 0; fj < 4; ++fj)
                acc[fi][fj] = __builtin_amdgcn_mfma_f32_16x16x32_bf16(
                    af[fi], bf[fj], acc[fi][fj], 0, 0, 0);
        __syncthreads();
    }

    #pragma unroll
    for (int fi = 0; fi < 4; ++fi) {
        const int g0 = gtile + wm * 64 + fi * 16 + ((lane >> 4) << 2);
        const float4 v1 = *(const float4*)&bih[g0];
        const float4 v2 = *(const float4*)&bhh[g0];
        float badd[4] = {v1.x + v2.x, v1.y + v2.y, v1.z + v2.z, v1.w + v2.w};
        #pragma unroll
        for (int fj = 0; fj < 4; ++fj) {
            const int m = mtile + wn * 64 + fj * 16 + (lane & 15);
            const int b = m & 63, s = m >> 6;
            float* dst = &xg[s * XG_SSTRIDE + b];
            #pragma unroll
            for (int r = 0; r < 4; ++r)
                dst[(g0 + r) * 64] = acc[fi][fj][r] + badd[r];
        }
    }
}

// --------------------------------------------------------- K2: LSTM (persistent)
// R10 structure (364us). THIS round's single change: packed publish.
// nonlin lanes write h into a 1KB LDS hex[batch][unit] tile -> barrier ->
// wave 0 alone re-reads 64x16B and issues contiguous dwordx4 sc0/sc1 stores
// (vs 256 scattered dwords from all waves), drains only its own queue, fires
// the flag. Wave 1 writes hidden history from hex (off critical path).
// Poll / stage / xg-prefetch placement byte-identical to R10.
#define LSTM_NBLK 64

__global__ __launch_bounds__(512, 2) void k2_lstm(
    const u16* __restrict__ Whh,     // [2048][512] bf16
    const float* __restrict__ xg,    // [S][G][B]
    u16* __restrict__ hbuf,          // [2][64][512] bf16 (zeroed)
    u16* __restrict__ hidden,        // [8192][512] bf16
    u32* __restrict__ flags)         // [64] on 128B-strided lines (zeroed)
{
    __shared__ __align__(16) u16 hl[16 * 528];   // [16 rows][512+16 pad] bf16
    __shared__ __align__(16) u16 hex[8 * 64];    // [batch][unit-in-block]

    const int t = threadIdx.x, lane = t & 63, w = t >> 6;   // 8 waves
    const int bg = blockIdx.x >> 3, ug = blockIdx.x & 7;
    const int j = lane & 15;
    const int kc8 = (lane >> 4) * 8;

    const int ubase = ug * 64 + w * 8;
    const int grow0 = (j & 3) * 512 + ubase + (j >> 2);
    const int grow1 = grow0 + 4;

    bf16x8 bw0[16], bw1[16];
    #pragma unroll
    for (int kk = 0; kk < 16; ++kk) {
        bw0[kk] = ld_frag(&Whh[grow0 * NH + kk * 32 + kc8]);
        bw1[kk] = ld_frag(&Whh[grow1 * NH + kk * 32 + kc8]);
    }
    #pragma unroll
    for (int kk = 0; kk < 16; ++kk) {     // pin weights (one-time)
        f32x4 w0 = __builtin_bit_cast(f32x4, bw0[kk]);
        f32x4 w1 = __builtin_bit_cast(f32x4, bw1[kk]);
        asm volatile("" : "+v"(w0), "+v"(w1));
        bw0[kk] = __builtin_bit_cast(bf16x8, w0);
        bw1[kk] = __builtin_bit_cast(bf16x8, w1);
    }

    {
        u16x8 z = {0, 0, 0, 0, 0, 0, 0, 0};
        *(u16x8*)&hl[(8 + (t >> 6)) * 528 + (t & 63) * 8] = z;
    }

    const int srow = t >> 6, scol = (t & 63) * 8;
    const int soff = (bg * 8 + srow) * NH + scol;
    u16* hl_w = &hl[srow * 528 + scol];

    const int p = lane & 3;
    const int q = (lane >> 2) & 3;
    const int bl = (lane >> 4) * 4 + p;          // batch local 0..7
    const bool act = lane < 32;
    const bool sl = act && ((lane & 4) == 0);    // q even: owns u32 pairs

    const int xoff0 = grow0 * 64 + bg * 8 + (lane >> 4) * 4;
    const int xoff1 = grow1 * 64 + bg * 8 + (lane >> 4) * 4;

    f32x4 xv0 = {0, 0, 0, 0}, xv1 = {0, 0, 0, 0};
    f32x4 xn0 = {0, 0, 0, 0}, xn1 = {0, 0, 0, 0};
    if (act) {
        xv0 = *(const f32x4*)&xg[xoff0];
        xv1 = *(const f32x4*)&xg[xoff1];
    }
    float cA = 0.f, cB = 0.f;

    for (int step = 0; step < NS; ++step) {
        // prefetch next step's xg FIRST (R10 placement; poll absorbs latency)
        if (act && step + 1 < NS) {
            const float* xb = &xg[(step + 1) * XG_SSTRIDE];
            prefetch16(xn0, &xb[xoff0]);
            prefetch16(xn1, &xb[xoff1]);
        }
        // every wave polls its group's 8 flags (8 lanes only)
        if (step > 0 && lane < 8) {
            const u32* fp = &flags[(bg * 8 + lane) * 32];
            while ((int)load_llc(fp) < step) __builtin_amdgcn_s_sleep(1);
        }
        // stage h_t (8KB) from LLC into LDS
        {
            f32x4 hv = load_llc16(&hbuf[(step & 1) * (NB * NH) + soff]);
            *(f32x4*)hl_w = hv;
        }
        __syncthreads();

        f32x4 a00 = {0, 0, 0, 0}, a01 = {0, 0, 0, 0};
        f32x4 a10 = {0, 0, 0, 0}, a11 = {0, 0, 0, 0};
        #pragma unroll
        for (int kk = 0; kk < 16; ++kk) {
            bf16x8 av = *(const bf16x8*)&hl[j * 528 + kk * 32 + kc8];
            if (kk & 1) {
                a01 = __builtin_amdgcn_mfma_f32_16x16x32_bf16(av, bw0[kk], a01, 0, 0, 0);
                a11 = __builtin_amdgcn_mfma_f32_16x16x32_bf16(av, bw1[kk], a11, 0, 0, 0);
            } else {
                a00 = __builtin_amdgcn_mfma_f32_16x16x32_bf16(av, bw0[kk], a00, 0, 0, 0);
                a10 = __builtin_amdgcn_mfma_f32_16x16x32_bf16(av, bw1[kk], a10, 0, 0, 0);
            }
        }

        float v0[4], v1[4];
        #pragma unroll
        for (int r = 0; r < 4; ++r) {
            v0[r] = a00[r] + a01[r] + xv0[r];
            v1[r] = a10[r] + a11[r] + xv1[r];
        }
        quad_transpose(v0, p);
        quad_transpose(v1, p);

        float h0 = lstm_cell(v0, cA);
        float h1 = lstm_cell(v1, cB);
        u32 hb0 = f2bf(h0), hb1 = f2bf(h1);
        u32 o0 = (u32)__shfl_xor((int)hb0, 4);   // partner holds unit q^1
        u32 o1 = (u32)__shfl_xor((int)hb1, 4);

        // gather h into hex[batch][unit]: pr0 = units (w8+q, w8+q+1), pr1 = +4
        if (sl) {
            u32* hx = (u32*)hex;
            hx[bl * 32 + (w * 8 + q) / 2]       = hb0 | (o0 << 16);
            hx[bl * 32 + (w * 8 + q + 4) / 2]   = hb1 | (o1 << 16);
        }
        xv0 = xn0; xv1 = xn1;
        __syncthreads();   // hex visible; hl safe to overwrite next step

        if (w == 0) {
            // packed publish: 64 lanes x 16B contiguous, single-wave drain
            if (step + 1 < NS) {
                u16x8 hv = *(const u16x8*)&hex[lane * 8];
                store_llc16(&hbuf[((step + 1) & 1) * (NB * NH)
                                  + (bg * 8 + (lane >> 3)) * NH
                                  + ug * 64 + (lane & 7) * 8], hv);
                asm volatile("s_waitcnt vmcnt(0)" ::: "memory");
                if (lane == 0)
                    store_llc(&flags[blockIdx.x * 32], (u32)(step + 1));
            }
        } else if (w == 1) {
            // hidden history from hex (plain stores, off critical path)
            u16x8 hv = *(const u16x8*)&hex[lane * 8];
            *(u16x8*)&hidden[((bg * 8 + (lane >> 3)) * NS + step) * NH
                             + ug * 64 + (lane & 7) * 8] = hv;
        }
    }
}

// ------------------------------------- K3: logits = hidden @ W_cls^T + b_cls
// mfma(A=hid, B=Wc): D rows = m (=b,s), cols = v -> coalesced u16x4/float4
// stores along s. PACK16: bf16 logits to workspace (halves logit traffic).
template <bool PACK16>
__global__ __launch_bounds__(256) void k3_cls(
    const u16* __restrict__ Wc, const u16* __restrict__ hid,
    const float* __restrict__ bcls,
    float* __restrict__ outf, u16* __restrict__ outb,
    float* __restrict__ lse)
{
    __shared__ __align__(16) u16 Al[128 * 32];   // Wc tile (v rows)
    __shared__ __align__(16) u16 Bl[128 * 32];   // hid tile (m rows)
    __shared__ float red[2][128];

    const int t = threadIdx.x;
    const int lane = t & 63, w = t >> 6;
    const int wm = w >> 1, wn = w & 1;
    const int vtile = blockIdx.y * 128, mtile = blockIdx.x * 128;

    const int srow = w * 16 + (lane >> 2);
    const int scol = (lane & 3) * 8;
    const u16* gA = &Wc[(vtile + srow) * NH + scol];
    const u16* gB = &hid[(mtile + srow) * NH + scol];
    u16* lA0 = &Al[(w * 16) * 32];
    u16* lA1 = &Al[(w * 16 + 64) * 32];
    u16* lB0 = &Bl[(w * 16) * 32];
    u16* lB1 = &Bl[(w * 16 + 64) * 32];

    f32x4 acc[4][4];
    for (int i = 0; i < 4; ++i)
        for (int j2 = 0; j2 < 4; ++j2) acc[i][j2] = {0.f, 0.f, 0.f, 0.f};

    const int kc8 = (lane >> 4) * 8;
    for (int kk = 0; kk < 16; ++kk) {
        const int k0 = kk * 32;
        gload_lds16(gA + k0,           lA0);
        gload_lds16(gA + 64 * NH + k0, lA1);
        gload_lds16(gB + k0,           lB0);
        gload_lds16(gB + 64 * NH + k0, lB1);
        __syncthreads();
        bf16x8 mf[4], vf[4];
        #pragma unroll
        for (int i = 0; i < 4; ++i) {
            mf[i] = ld_frag(&Bl[(wm * 64 + i * 16 + (lane & 15)) * 32 + kc8]);
            vf[i] = ld_frag(&Al[(wn * 64 + i * 16 + (lane & 15)) * 32 + kc8]);
        }
        #pragma unroll
        for (int fi = 0; fi < 4; ++fi)
            #pragma unroll
            for (int fj = 0; fj < 4; ++fj)
                acc[fi][fj] = __builtin_amdgcn_mfma_f32_16x16x32_bf16(
                    mf[fi], vf[fj], acc[fi][fj], 0, 0, 0);
        __syncthreads();
    }

    float lsum[4][4];
    #pragma unroll
    for (int fi = 0; fi < 4; ++fi)
        #pragma unroll
        for (int r = 0; r < 4; ++r) lsum[fi][r] = 0.f;

    #pragma unroll
    for (int fj = 0; fj < 4; ++fj) {
        const int v = vtile + wn * 64 + fj * 16 + (lane & 15);
        const bool vok = (v < NV);
        const float bc = vok ? bcls[v] : 0.f;
        #pragma unroll
        for (int fi = 0; fi < 4; ++fi) {
            const int m = mtile + wm * 64 + fi * 16 + ((lane >> 4) << 2);
            const int b = m >> 7, s = m & 127;
            float lg[4];
            #pragma unroll
            for (int r = 0; r < 4; ++r) {
                lg[r] = acc[fi][fj][r] + bc;
                if (vok) lsum[fi][r] += __expf(lg[r]);
            }
            if (vok) {
                if (PACK16) {
                    u16x4 o = {f2bf(lg[0]), f2bf(lg[1]), f2bf(lg[2]), f2bf(lg[3])};
                    *(u16x4*)&outb[b * OUT_BSTRIDE + v * NS + s] = o;
                } else {
                    float4 o = {lg[0], lg[1], lg[2], lg[3]};
                    *(float4*)&outf[b * OUT_BSTRIDE + v * NS + s] = o;
                }
            }
        }
    }

    #pragma unroll
    for (int fi = 0; fi < 4; ++fi)
        #pragma unroll
        for (int r = 0; r < 4; ++r) {
            float sv = lsum[fi][r];
            sv += __shfl_xor(sv, 1);
            sv += __shfl_xor(sv, 2);
            sv += __shfl_xor(sv, 4);
            sv += __shfl_xor(sv, 8);
            lsum[fi][r] = sv;
        }
    if ((lane & 15) == 0) {
        #pragma unroll
        for (int fi = 0; fi < 4; ++fi)
            #pragma unroll
            for (int r = 0; r < 4; ++r)
                red[wn][wm * 64 + fi * 16 + ((lane >> 4) << 2) + r] = lsum[fi][r];
    }
    __syncthreads();
    if (t < 128) {
        const int m = mtile + t;
        atomicAdd(&lse[m], red[0][t] + red[1][t]);
    }
}

// ------------------------------------------------------------- K4/K5 epilogue
__global__ void k4_log(const float* __restrict__ lse, float* __restrict__ ll) {
    int i = blockIdx.x * 256 + threadIdx.x;
    if (i < NBS) ll[i] = logf(lse[i]);
}

// in-place f32 path (fallback)
__global__ void k5_norm(float* __restrict__ out, const float* __restrict__ ll) {
    const int total4 = NB * NV * NS / 4;   // 16,384,000
    float4* o4 = (float4*)out;
    for (int i = blockIdx.x * blockDim.x + threadIdx.x; i < total4;
         i += gridDim.x * blockDim.x) {
        const int i4 = i * 4;
        const int b = i4 / OUT_BSTRIDE;
        const int s = i4 & 127;
        float4 v = o4[i];
        const float4 l = *(const float4*)&ll[b * NS + s];
        v.x -= l.x; v.y -= l.y; v.z -= l.z; v.w -= l.w;
        o4[i] = v;
    }
}

// bf16-logits path: read u16x4 from ws, write f32 out
__global__ void k5_bf16(float* __restrict__ out, const u16* __restrict__ lgb,
                        const float* __restrict__ ll) {
    const int total4 = NB * NV * NS / 4;
    float4* o4 = (float4*)out;
    const u16x4* l4 = (const u16x4*)lgb;
    for (int i = blockIdx.x * blockDim.x + threadIdx.x; i < total4;
         i += gridDim.x * blockDim.x) {
        const int i4 = i * 4;
        const int b = i4 / OUT_BSTRIDE;
        const int s = i4 & 127;
        u16x4 g = l4[i];
        const float4 l = *(const float4*)&ll[b * NS + s];
        float4 v;
        v.x = bf2f(g[0]) - l.x;
        v.y = bf2f(g[1]) - l.y;
        v.z = bf2f(g[2]) - l.z;
        v.w = bf2f(g[3]) - l.w;
        o4[i] = v;
    }
}

// ---------------------------------------------------------------------------
extern "C" void kernel_launch(void* const* d_in, const int* in_sizes, int n_in,
                              void* d_out, int out_size, void* d_ws, size_t ws_size,
                              hipStream_t stream) {
    const int*   toks   = (const int*)d_in[0];
    const float* emb_f  = (const float*)d_in[1];
    const float* Wih_f  = (const float*)d_in[2];
    const float* Whh_f  = (const float*)d_in[3];
    const float* bih    = (const float*)d_in[4];
    const float* bhh    = (const float*)d_in[5];
    const float* Wcls_f = (const float*)d_in[6];
    const float* bcls   = (const float*)d_in[7];
    float* out = (float*)d_out;
    char*  ws  = (char*)d_ws;

    // workspace layout (bytes)
    u32*   flags  = (u32*)(ws + 0);            // 8192 (64 x 128B lines)
    float* lse    = (float*)(ws + 8192);       // 32768
    float* loglse = (float*)(ws + 40960);      // 32768
    u16*   hbuf   = (u16*)(ws + 73728);        // 131072 (zeroed: h0 = 0)
    u16*   embb   = (u16*)(ws + 204800);       // 4,096,000
    u16*   wihb   = (u16*)(ws + 4300800);      // 1,048,576
    u16*   whhb   = (u16*)(ws + 5349376);      // 2,097,152
    u16*   wclsb  = (u16*)(ws + 7446528);      // 8,388,608 (padded 8192 rows)
    u16*   hidden = (u16*)(ws + 15835136);     // 8,388,608
    u16*   lgb    = (u16*)(ws + 24223744);     // 131,072,000 (bf16 logits, optional)
    const bool bigws = ws_size >= (size_t)24223744 + (size_t)NB * NV * NS * 2;

    // x_gates f32 [S][G][B] lives in d_out scratch (16.8M floats < 65.5M)
    float* xg = out;

    hipMemsetAsync(ws, 0, 204800, stream);     // flags + lse + loglse + hbuf
    hipMemsetAsync((char*)wclsb + NV * NH * 2, 0, (NVP - NV) * NH * 2, stream);

    cvt_all<<<2048, 256, 0, stream>>>(emb_f, Wih_f, Whh_f, Wcls_f,
                                      embb, wihb, whhb, wclsb);

    k1_xgates<<<dim3(64, 16), 256, 0, stream>>>(wihb, embb, toks, bih, bhh, xg);
    k2_lstm<<<LSTM_NBLK, 512, 0, stream>>>(whhb, xg, hbuf, hidden, flags);
    if (bigws) {
        k3_cls<true><<<dim3(64, 64), 256, 0, stream>>>(wclsb, hidden, bcls,
                                                       out, lgb, lse);
        k4_log<<<32, 256, 0, stream>>>(lse, loglse);
        k5_bf16<<<2048, 256, 0, stream>>>(out, lgb, loglse);
    } else {
        k3_cls<false><<<dim3(64, 64), 256, 0, stream>>>(wclsb, hidden, bcls,
                                                        out, lgb, lse);
        k4_log<<<32, 256, 0, stream>>>(lse, loglse);
        k5_norm<<<2048, 256, 0, stream>>>(out, loglse);
    }
}

// Round 13
// 604.378 us; speedup vs baseline: 1.0925x; 1.0925x over previous
//
#include <hip/hip_runtime.h>

// ---------------------------------------------------------------------------
// PoetryModel: embed -> x_gates GEMM -> LSTM(128 steps) -> classifier GEMM
//              -> log_softmax over V -> out (B, V, S) f32
// B=64 S=128 V=8000 E=256 H=512 G=4H=2048
// ---------------------------------------------------------------------------

using u16   = unsigned short;
using u32   = unsigned int;
using u16x4 = __attribute__((ext_vector_type(4))) u16;
using u16x8 = __attribute__((ext_vector_type(8))) u16;
using bf16x8 = __attribute__((ext_vector_type(8))) __bf16;
using f32x4 = __attribute__((ext_vector_type(4))) float;

#define NB   64        // batch
#define NS   128       // seq len
#define NV   8000      // vocab
#define NVP  8192      // vocab padded to tile
#define NE   256       // embed dim
#define NH   512       // hidden
#define NG   2048      // 4*H
#define NBS  8192      // B*S
#define OUT_BSTRIDE 1024000   // V*S
#define XG_SSTRIDE  131072    // G*B

__device__ inline u16 f2bf(float f) {
    unsigned x = __builtin_bit_cast(unsigned, f);
    unsigned r = (x + 0x7FFFu + ((x >> 16) & 1u)) >> 16;
    return (u16)r;
}
__device__ inline float bf2f(u16 x) {
    u32 u = ((u32)x) << 16;
    return __builtin_bit_cast(float, u);
}

__device__ inline bf16x8 ld_frag(const u16* p) {
    u16x8 v = *(const u16x8*)p;
    return __builtin_bit_cast(bf16x8, v);
}

// LLC-coherent ops: bypass L1+L2, never create/consume dirty L2 lines.
__device__ inline u32 load_llc(const u32* p) {
    u32 v;
    asm volatile("global_load_dword %0, %1, off sc0 sc1\n\t"
                 "s_waitcnt vmcnt(0)"
                 : "=v"(v) : "v"(p) : "memory");
    return v;
}
__device__ inline f32x4 load_llc16(const void* p) {
    f32x4 v;
    asm volatile("global_load_dwordx4 %0, %1, off sc0 sc1\n\t"
                 "s_waitcnt vmcnt(0)"
                 : "=v"(v) : "v"(p) : "memory");
    return v;
}
__device__ inline void store_llc(u32* p, u32 v) {
    asm volatile("global_store_dword %0, %1, off sc0 sc1"
                 :: "v"(p), "v"(v) : "memory");
}
// plain cached load, NO waitcnt: covered by a later vmcnt(0) before use
__device__ inline void prefetch16(f32x4& d, const float* p) {
    asm volatile("global_load_dwordx4 %0, %1, off"
                 : "=v"(d) : "v"(p) : "memory");
}

// direct global->LDS copy, 16B per lane (dst must be wave-uniform base)
__device__ inline void gload_lds16(const u16* g, u16* l) {
    __builtin_amdgcn_global_load_lds(
        (const __attribute__((address_space(1))) unsigned int*)(const void*)g,
        (__attribute__((address_space(3))) unsigned int*)(void*)l,
        16, 0, 0);
}

// 4x4 transpose across lane quad {p} x element {r} (verified round 3)
__device__ inline void quad_transpose(float v[4], int p) {
    float tb[4];
    #pragma unroll
    for (int q2 = 0; q2 < 4; ++q2) tb[q2] = __shfl_xor(v[q2 ^ 2], 2);
    #pragma unroll
    for (int q2 = 0; q2 < 4; ++q2) v[q2] = (((q2 ^ p) & 2) ? tb[q2] : v[q2]);
    #pragma unroll
    for (int q2 = 0; q2 < 4; ++q2) tb[q2] = __shfl_xor(v[q2 ^ 1], 1);
    #pragma unroll
    for (int q2 = 0; q2 < 4; ++q2) v[q2] = (((q2 ^ p) & 1) ? tb[q2] : v[q2]);
}

__device__ inline float lstm_cell(const float v[4], float& c) {
    float i_ = 1.f / (1.f + __expf(-v[0]));
    float f_ = 1.f / (1.f + __expf(-v[1]));
    float e2 = __expf(2.f * v[2]);
    float g_ = 1.f - 2.f / (e2 + 1.f);
    float o_ = 1.f / (1.f + __expf(-v[3]));
    c = f_ * c + i_ * g_;
    float e2c = __expf(2.f * c);
    return o_ * (1.f - 2.f / (e2c + 1.f));
}

// ------------------------------------------------- merged weight converts
__global__ void cvt_all(const float* __restrict__ e,  const float* __restrict__ wi,
                        const float* __restrict__ wh, const float* __restrict__ wc,
                        u16* __restrict__ de,  u16* __restrict__ dwi,
                        u16* __restrict__ dwh, u16* __restrict__ dwc) {
    const int N0 = NV * NE / 8, N1 = NG * NE / 8, N2 = NG * NH / 8, N3 = NV * NH / 8;
    const int total = N0 + N1 + N2 + N3;
    for (int i = blockIdx.x * blockDim.x + threadIdx.x; i < total;
         i += gridDim.x * blockDim.x) {
        const float* s; u16* d; int j;
        if (i < N0)                { s = e;  d = de;  j = i; }
        else if (i < N0 + N1)      { s = wi; d = dwi; j = i - N0; }
        else if (i < N0 + N1 + N2) { s = wh; d = dwh; j = i - N0 - N1; }
        else                       { s = wc; d = dwc; j = i - N0 - N1 - N2; }
        const float4* s4 = (const float4*)s;
        float4 a = s4[2 * j], b = s4[2 * j + 1];
        u16x8 o;
        o[0] = f2bf(a.x); o[1] = f2bf(a.y); o[2] = f2bf(a.z); o[3] = f2bf(a.w);
        o[4] = f2bf(b.x); o[5] = f2bf(b.y); o[6] = f2bf(b.z); o[7] = f2bf(b.w);
        ((u16x8*)d)[j] = o;
    }
}

// ------------------------------------------------- K1: x_gates = x @ W_ih^T
__global__ __launch_bounds__(256) void k1_xgates(
    const u16* __restrict__ Wih, const u16* __restrict__ emb,
    const int* __restrict__ toks,
    const float* __restrict__ bih, const float* __restrict__ bhh,
    float* __restrict__ xg)
{
    __shared__ u16x8 Al8[512];   // [128][32] bf16
    __shared__ u16x8 Bl8[512];
    u16* Al = (u16*)Al8;
    u16* Bl = (u16*)Bl8;

    const int t = threadIdx.x;
    const int lane = t & 63, w = t >> 6;
    const int wm = w >> 1, wn = w & 1;
    const int gtile = blockIdx.y * 128, mtile = blockIdx.x * 128;

    const int r0 = t >> 2, r1 = r0 + 64, q = t & 3;
    const int m0 = mtile + r0, m1 = mtile + r1;
    const int tok0 = toks[(m0 & 63) * NS + (m0 >> 6)];
    const int tok1 = toks[(m1 & 63) * NS + (m1 >> 6)];

    f32x4 acc[4][4];
    for (int i = 0; i < 4; ++i)
        for (int j = 0; j < 4; ++j) acc[i][j] = {0.f, 0.f, 0.f, 0.f};

    const int kc8 = (lane >> 4) * 8;
    for (int kk = 0; kk < 8; ++kk) {
        const int k0 = kk * 32;
        *(u16x8*)&Al[t * 8]         = *(const u16x8*)&Wih[(gtile + r0) * NE + k0 + q * 8];
        *(u16x8*)&Al[(t + 256) * 8] = *(const u16x8*)&Wih[(gtile + r1) * NE + k0 + q * 8];
        *(u16x8*)&Bl[t * 8]         = *(const u16x8*)&emb[tok0 * NE + k0 + q * 8];
        *(u16x8*)&Bl[(t + 256) * 8] = *(const u16x8*)&emb[tok1 * NE + k0 + q * 8];
        __syncthreads();
        bf16x8 af[4], bf[4];
        #pragma unroll
        for (int i = 0; i < 4; ++i) {
            af[i] = ld_frag(&Al[(wm * 64 + i * 16 + (lane & 15)) * 32 + kc8]);
            bf[i] = ld_frag(&Bl[(wn * 64 + i * 16 + (lane & 15)) * 32 + kc8]);
        }
        #pragma unroll
        for (int fi = 0; fi < 4; ++fi)
            #pragma unroll
            for (int fj = 0; fj < 4; ++fj)
                acc[fi][fj] = __builtin_amdgcn_mfma_f32_16x16x32_bf16(
                    af[fi], bf[fj], acc[fi][fj], 0, 0, 0);
        __syncthreads();
    }

    #pragma unroll
    for (int fi = 0; fi < 4; ++fi) {
        const int g0 = gtile + wm * 64 + fi * 16 + ((lane >> 4) << 2);
        const float4 v1 = *(const float4*)&bih[g0];
        const float4 v2 = *(const float4*)&bhh[g0];
        float badd[4] = {v1.x + v2.x, v1.y + v2.y, v1.z + v2.z, v1.w + v2.w};
        #pragma unroll
        for (int fj = 0; fj < 4; ++fj) {
            const int m = mtile + wn * 64 + fj * 16 + (lane & 15);
            const int b = m & 63, s = m >> 6;
            float* dst = &xg[s * XG_SSTRIDE + b];
            #pragma unroll
            for (int r = 0; r < 4; ++r)
                dst[(g0 + r) * 64] = acc[fi][fj][r] + badd[r];
        }
    }
}

// --------------------------------------------------------- K2: LSTM (persistent)
// R10 best (364us): byte-identical revert. 64 blocks = 8 batch-groups x
// 8 unit-slices, weights register-resident, 528-stride LDS staging, 8-flag
// group rendezvous at LLC (sc0 sc1), 8 polling lanes/wave, prefetch-first,
// hidden-history after the flag. R12's packed-publish experiment regressed
// (+67us: serialized single-wave publish tail + hex bank conflicts) — the
// scattered per-wave publish overlapping nonlin is the measured optimum.
#define LSTM_NBLK 64

__global__ __launch_bounds__(512, 2) void k2_lstm(
    const u16* __restrict__ Whh,     // [2048][512] bf16
    const float* __restrict__ xg,    // [S][G][B]
    u16* __restrict__ hbuf,          // [2][64][512] bf16 (zeroed)
    u16* __restrict__ hidden,        // [8192][512] bf16
    u32* __restrict__ flags)         // [64] on 128B-strided lines (zeroed)
{
    __shared__ __align__(16) u16 hl[16 * 528];   // [16 rows][512+16 pad] bf16

    const int t = threadIdx.x, lane = t & 63, w = t >> 6;   // 8 waves
    const int bg = blockIdx.x >> 3, ug = blockIdx.x & 7;
    const int j = lane & 15;
    const int kc8 = (lane >> 4) * 8;

    const int ubase = ug * 64 + w * 8;
    const int grow0 = (j & 3) * 512 + ubase + (j >> 2);
    const int grow1 = grow0 + 4;

    bf16x8 bw0[16], bw1[16];
    #pragma unroll
    for (int kk = 0; kk < 16; ++kk) {
        bw0[kk] = ld_frag(&Whh[grow0 * NH + kk * 32 + kc8]);
        bw1[kk] = ld_frag(&Whh[grow1 * NH + kk * 32 + kc8]);
    }
    #pragma unroll
    for (int kk = 0; kk < 16; ++kk) {     // pin weights (one-time)
        f32x4 w0 = __builtin_bit_cast(f32x4, bw0[kk]);
        f32x4 w1 = __builtin_bit_cast(f32x4, bw1[kk]);
        asm volatile("" : "+v"(w0), "+v"(w1));
        bw0[kk] = __builtin_bit_cast(bf16x8, w0);
        bw1[kk] = __builtin_bit_cast(bf16x8, w1);
    }

    {
        u16x8 z = {0, 0, 0, 0, 0, 0, 0, 0};
        *(u16x8*)&hl[(8 + (t >> 6)) * 528 + (t & 63) * 8] = z;
    }

    const int srow = t >> 6, scol = (t & 63) * 8;
    const int soff = (bg * 8 + srow) * NH + scol;
    u16* hl_w = &hl[srow * 528 + scol];

    const int p = lane & 3;
    const int q = (lane >> 2) & 3;
    const int batg = bg * 8 + (lane >> 4) * 4 + p;
    const int un0 = ubase + q;
    const bool act = lane < 32;
    const bool sl = act && ((lane & 4) == 0);

    const int xoff0 = grow0 * 64 + bg * 8 + (lane >> 4) * 4;
    const int xoff1 = grow1 * 64 + bg * 8 + (lane >> 4) * 4;

    f32x4 xv0 = {0, 0, 0, 0}, xv1 = {0, 0, 0, 0};
    f32x4 xn0 = {0, 0, 0, 0}, xn1 = {0, 0, 0, 0};
    if (act) {
        xv0 = *(const f32x4*)&xg[xoff0];
        xv1 = *(const f32x4*)&xg[xoff1];
    }
    float cA = 0.f, cB = 0.f;

    for (int step = 0; step < NS; ++step) {
        if (act && step + 1 < NS) {
            const float* xb = &xg[(step + 1) * XG_SSTRIDE];
            prefetch16(xn0, &xb[xoff0]);
            prefetch16(xn1, &xb[xoff1]);
        }
        if (step > 0 && lane < 8) {
            const u32* fp = &flags[(bg * 8 + lane) * 32];
            while ((int)load_llc(fp) < step) __builtin_amdgcn_s_sleep(1);
        }
        {
            f32x4 hv = load_llc16(&hbuf[(step & 1) * (NB * NH) + soff]);
            *(f32x4*)hl_w = hv;
        }
        __syncthreads();

        f32x4 a00 = {0, 0, 0, 0}, a01 = {0, 0, 0, 0};
        f32x4 a10 = {0, 0, 0, 0}, a11 = {0, 0, 0, 0};
        #pragma unroll
        for (int kk = 0; kk < 16; ++kk) {
            bf16x8 av = *(const bf16x8*)&hl[j * 528 + kk * 32 + kc8];
            if (kk & 1) {
                a01 = __builtin_amdgcn_mfma_f32_16x16x32_bf16(av, bw0[kk], a01, 0, 0, 0);
                a11 = __builtin_amdgcn_mfma_f32_16x16x32_bf16(av, bw1[kk], a11, 0, 0, 0);
            } else {
                a00 = __builtin_amdgcn_mfma_f32_16x16x32_bf16(av, bw0[kk], a00, 0, 0, 0);
                a10 = __builtin_amdgcn_mfma_f32_16x16x32_bf16(av, bw1[kk], a10, 0, 0, 0);
            }
        }

        float v0[4], v1[4];
        #pragma unroll
        for (int r = 0; r < 4; ++r) {
            v0[r] = a00[r] + a01[r] + xv0[r];
            v1[r] = a10[r] + a11[r] + xv1[r];
        }
        quad_transpose(v0, p);
        quad_transpose(v1, p);

        float h0 = lstm_cell(v0, cA);
        float h1 = lstm_cell(v1, cB);
        u32 hb0 = f2bf(h0), hb1 = f2bf(h1);
        u32 o0 = (u32)__shfl_xor((int)hb0, 4);
        u32 o1 = (u32)__shfl_xor((int)hb1, 4);
        u32 pr0 = hb0 | (o0 << 16);
        u32 pr1 = hb1 | (o1 << 16);

        if (sl) {
            u16* hn = hbuf + ((step & 1) ^ 1) * (NB * NH);
            store_llc((u32*)&hn[batg * NH + un0], pr0);
            store_llc((u32*)&hn[batg * NH + un0 + 4], pr1);
        }
        xv0 = xn0; xv1 = xn1;
        __syncthreads();

        if (step + 1 < NS && t == 0)
            store_llc(&flags[blockIdx.x * 32], (u32)(step + 1));

        if (sl) {
            *(u32*)&hidden[(batg * NS + step) * NH + un0] = pr0;
            *(u32*)&hidden[(batg * NS + step) * NH + un0 + 4] = pr1;
        }
    }
}

// ------------------------------------- K3: logits = hidden @ W_cls^T + b_cls
// mfma(A=hid, B=Wc): D rows = m (=b,s), cols = v -> coalesced u16x4/float4
// stores along s. PACK16: bf16 logits to workspace (halves logit traffic).
template <bool PACK16>
__global__ __launch_bounds__(256) void k3_cls(
    const u16* __restrict__ Wc, const u16* __restrict__ hid,
    const float* __restrict__ bcls,
    float* __restrict__ outf, u16* __restrict__ outb,
    float* __restrict__ lse)
{
    __shared__ __align__(16) u16 Al[128 * 32];   // Wc tile (v rows)
    __shared__ __align__(16) u16 Bl[128 * 32];   // hid tile (m rows)
    __shared__ float red[2][128];

    const int t = threadIdx.x;
    const int lane = t & 63, w = t >> 6;
    const int wm = w >> 1, wn = w & 1;
    const int vtile = blockIdx.y * 128, mtile = blockIdx.x * 128;

    const int srow = w * 16 + (lane >> 2);
    const int scol = (lane & 3) * 8;
    const u16* gA = &Wc[(vtile + srow) * NH + scol];
    const u16* gB = &hid[(mtile + srow) * NH + scol];
    u16* lA0 = &Al[(w * 16) * 32];
    u16* lA1 = &Al[(w * 16 + 64) * 32];
    u16* lB0 = &Bl[(w * 16) * 32];
    u16* lB1 = &Bl[(w * 16 + 64) * 32];

    f32x4 acc[4][4];
    for (int i = 0; i < 4; ++i)
        for (int j2 = 0; j2 < 4; ++j2) acc[i][j2] = {0.f, 0.f, 0.f, 0.f};

    const int kc8 = (lane >> 4) * 8;
    for (int kk = 0; kk < 16; ++kk) {
        const int k0 = kk * 32;
        gload_lds16(gA + k0,           lA0);
        gload_lds16(gA + 64 * NH + k0, lA1);
        gload_lds16(gB + k0,           lB0);
        gload_lds16(gB + 64 * NH + k0, lB1);
        __syncthreads();
        bf16x8 mf[4], vf[4];
        #pragma unroll
        for (int i = 0; i < 4; ++i) {
            mf[i] = ld_frag(&Bl[(wm * 64 + i * 16 + (lane & 15)) * 32 + kc8]);
            vf[i] = ld_frag(&Al[(wn * 64 + i * 16 + (lane & 15)) * 32 + kc8]);
        }
        #pragma unroll
        for (int fi = 0; fi < 4; ++fi)
            #pragma unroll
            for (int fj = 0; fj < 4; ++fj)
                acc[fi][fj] = __builtin_amdgcn_mfma_f32_16x16x32_bf16(
                    mf[fi], vf[fj], acc[fi][fj], 0, 0, 0);
        __syncthreads();
    }

    float lsum[4][4];
    #pragma unroll
    for (int fi = 0; fi < 4; ++fi)
        #pragma unroll
        for (int r = 0; r < 4; ++r) lsum[fi][r] = 0.f;

    #pragma unroll
    for (int fj = 0; fj < 4; ++fj) {
        const int v = vtile + wn * 64 + fj * 16 + (lane & 15);
        const bool vok = (v < NV);
        const float bc = vok ? bcls[v] : 0.f;
        #pragma unroll
        for (int fi = 0; fi < 4; ++fi) {
            const int m = mtile + wm * 64 + fi * 16 + ((lane >> 4) << 2);
            const int b = m >> 7, s = m & 127;
            float lg[4];
            #pragma unroll
            for (int r = 0; r < 4; ++r) {
                lg[r] = acc[fi][fj][r] + bc;
                if (vok) lsum[fi][r] += __expf(lg[r]);
            }
            if (vok) {
                if (PACK16) {
                    u16x4 o = {f2bf(lg[0]), f2bf(lg[1]), f2bf(lg[2]), f2bf(lg[3])};
                    *(u16x4*)&outb[b * OUT_BSTRIDE + v * NS + s] = o;
                } else {
                    float4 o = {lg[0], lg[1], lg[2], lg[3]};
                    *(float4*)&outf[b * OUT_BSTRIDE + v * NS + s] = o;
                }
            }
        }
    }

    #pragma unroll
    for (int fi = 0; fi < 4; ++fi)
        #pragma unroll
        for (int r = 0; r < 4; ++r) {
            float sv = lsum[fi][r];
            sv += __shfl_xor(sv, 1);
            sv += __shfl_xor(sv, 2);
            sv += __shfl_xor(sv, 4);
            sv += __shfl_xor(sv, 8);
            lsum[fi][r] = sv;
        }
    if ((lane & 15) == 0) {
        #pragma unroll
        for (int fi = 0; fi < 4; ++fi)
            #pragma unroll
            for (int r = 0; r < 4; ++r)
                red[wn][wm * 64 + fi * 16 + ((lane >> 4) << 2) + r] = lsum[fi][r];
    }
    __syncthreads();
    if (t < 128) {
        const int m = mtile + t;
        atomicAdd(&lse[m], red[0][t] + red[1][t]);
    }
}

// ------------------------------------------------------------- K4/K5 epilogue
__global__ void k4_log(const float* __restrict__ lse, float* __restrict__ ll) {
    int i = blockIdx.x * 256 + threadIdx.x;
    if (i < NBS) ll[i] = logf(lse[i]);
}

// in-place f32 path (fallback)
__global__ void k5_norm(float* __restrict__ out, const float* __restrict__ ll) {
    const int total4 = NB * NV * NS / 4;   // 16,384,000
    float4* o4 = (float4*)out;
    for (int i = blockIdx.x * blockDim.x + threadIdx.x; i < total4;
         i += gridDim.x * blockDim.x) {
        const int i4 = i * 4;
        const int b = i4 / OUT_BSTRIDE;
        const int s = i4 & 127;
        float4 v = o4[i];
        const float4 l = *(const float4*)&ll[b * NS + s];
        v.x -= l.x; v.y -= l.y; v.z -= l.z; v.w -= l.w;
        o4[i] = v;
    }
}

// bf16-logits path: read u16x4 from ws, write f32 out
__global__ void k5_bf16(float* __restrict__ out, const u16* __restrict__ lgb,
                        const float* __restrict__ ll) {
    const int total4 = NB * NV * NS / 4;
    float4* o4 = (float4*)out;
    const u16x4* l4 = (const u16x4*)lgb;
    for (int i = blockIdx.x * blockDim.x + threadIdx.x; i < total4;
         i += gridDim.x * blockDim.x) {
        const int i4 = i * 4;
        const int b = i4 / OUT_BSTRIDE;
        const int s = i4 & 127;
        u16x4 g = l4[i];
        const float4 l = *(const float4*)&ll[b * NS + s];
        float4 v;
        v.x = bf2f(g[0]) - l.x;
        v.y = bf2f(g[1]) - l.y;
        v.z = bf2f(g[2]) - l.z;
        v.w = bf2f(g[3]) - l.w;
        o4[i] = v;
    }
}

// ---------------------------------------------------------------------------
extern "C" void kernel_launch(void* const* d_in, const int* in_sizes, int n_in,
                              void* d_out, int out_size, void* d_ws, size_t ws_size,
                              hipStream_t stream) {
    const int*   toks   = (const int*)d_in[0];
    const float* emb_f  = (const float*)d_in[1];
    const float* Wih_f  = (const float*)d_in[2];
    const float* Whh_f  = (const float*)d_in[3];
    const float* bih    = (const float*)d_in[4];
    const float* bhh    = (const float*)d_in[5];
    const float* Wcls_f = (const float*)d_in[6];
    const float* bcls   = (const float*)d_in[7];
    float* out = (float*)d_out;
    char*  ws  = (char*)d_ws;

    // workspace layout (bytes)
    u32*   flags  = (u32*)(ws + 0);            // 8192 (64 x 128B lines)
    float* lse    = (float*)(ws + 8192);       // 32768
    float* loglse = (float*)(ws + 40960);      // 32768
    u16*   hbuf   = (u16*)(ws + 73728);        // 131072 (zeroed: h0 = 0)
    u16*   embb   = (u16*)(ws + 204800);       // 4,096,000
    u16*   wihb   = (u16*)(ws + 4300800);      // 1,048,576
    u16*   whhb   = (u16*)(ws + 5349376);      // 2,097,152
    u16*   wclsb  = (u16*)(ws + 7446528);      // 8,388,608 (padded 8192 rows)
    u16*   hidden = (u16*)(ws + 15835136);     // 8,388,608
    u16*   lgb    = (u16*)(ws + 24223744);     // 131,072,000 (bf16 logits, optional)
    const bool bigws = ws_size >= (size_t)24223744 + (size_t)NB * NV * NS * 2;

    // x_gates f32 [S][G][B] lives in d_out scratch (16.8M floats < 65.5M)
    float* xg = out;

    hipMemsetAsync(ws, 0, 204800, stream);     // flags + lse + loglse + hbuf
    hipMemsetAsync((char*)wclsb + NV * NH * 2, 0, (NVP - NV) * NH * 2, stream);

    cvt_all<<<2048, 256, 0, stream>>>(emb_f, Wih_f, Whh_f, Wcls_f,
                                      embb, wihb, whhb, wclsb);

    k1_xgates<<<dim3(64, 16), 256, 0, stream>>>(wihb, embb, toks, bih, bhh, xg);
    k2_lstm<<<LSTM_NBLK, 512, 0, stream>>>(whhb, xg, hbuf, hidden, flags);
    if (bigws) {
        k3_cls<true><<<dim3(64, 64), 256, 0, stream>>>(wclsb, hidden, bcls,
                                                       out, lgb, lse);
        k4_log<<<32, 256, 0, stream>>>(lse, loglse);
        k5_bf16<<<2048, 256, 0, stream>>>(out, lgb, loglse);
    } else {
        k3_cls<false><<<dim3(64, 64), 256, 0, stream>>>(wclsb, hidden, bcls,
                                                        out, lgb, lse);
        k4_log<<<32, 256, 0, stream>>>(lse, loglse);
        k5_norm<<<2048, 256, 0, stream>>>(out, loglse);
    }
}

// Round 14
// 601.205 us; speedup vs baseline: 1.0983x; 1.0053x over previous
//
#include <hip/hip_runtime.h>

// ---------------------------------------------------------------------------
// PoetryModel: embed -> x_gates GEMM -> LSTM(128 steps) -> classifier GEMM
//              -> log_softmax over V -> out (B, V, S) f32
// B=64 S=128 V=8000 E=256 H=512 G=4H=2048
// ---------------------------------------------------------------------------

using u16   = unsigned short;
using u32   = unsigned int;
using u16x4 = __attribute__((ext_vector_type(4))) u16;
using u16x8 = __attribute__((ext_vector_type(8))) u16;
using bf16x8 = __attribute__((ext_vector_type(8))) __bf16;
using f32x4 = __attribute__((ext_vector_type(4))) float;

#define NB   64        // batch
#define NS   128       // seq len
#define NV   8000      // vocab
#define NVP  8192      // vocab padded to tile
#define NE   256       // embed dim
#define NH   512       // hidden
#define NG   2048      // 4*H
#define NBS  8192      // B*S
#define OUT_BSTRIDE 1024000   // V*S
#define XG_SSTRIDE  131072    // G*B

__device__ inline u16 f2bf(float f) {
    unsigned x = __builtin_bit_cast(unsigned, f);
    unsigned r = (x + 0x7FFFu + ((x >> 16) & 1u)) >> 16;
    return (u16)r;
}
__device__ inline float bf2f(u16 x) {
    u32 u = ((u32)x) << 16;
    return __builtin_bit_cast(float, u);
}

__device__ inline bf16x8 ld_frag(const u16* p) {
    u16x8 v = *(const u16x8*)p;
    return __builtin_bit_cast(bf16x8, v);
}

// LLC-coherent ops: bypass L1+L2, never create/consume dirty L2 lines.
__device__ inline u32 load_llc(const u32* p) {
    u32 v;
    asm volatile("global_load_dword %0, %1, off sc0 sc1\n\t"
                 "s_waitcnt vmcnt(0)"
                 : "=v"(v) : "v"(p) : "memory");
    return v;
}
__device__ inline f32x4 load_llc16(const void* p) {
    f32x4 v;
    asm volatile("global_load_dwordx4 %0, %1, off sc0 sc1\n\t"
                 "s_waitcnt vmcnt(0)"
                 : "=v"(v) : "v"(p) : "memory");
    return v;
}
__device__ inline void store_llc(u32* p, u32 v) {
    asm volatile("global_store_dword %0, %1, off sc0 sc1"
                 :: "v"(p), "v"(v) : "memory");
}
// plain cached load, NO waitcnt: covered by a later vmcnt(0) before use
__device__ inline void prefetch16(f32x4& d, const float* p) {
    asm volatile("global_load_dwordx4 %0, %1, off"
                 : "=v"(d) : "v"(p) : "memory");
}

// direct global->LDS copy, 16B per lane (dst must be wave-uniform base)
__device__ inline void gload_lds16(const u16* g, u16* l) {
    __builtin_amdgcn_global_load_lds(
        (const __attribute__((address_space(1))) unsigned int*)(const void*)g,
        (__attribute__((address_space(3))) unsigned int*)(void*)l,
        16, 0, 0);
}

// 4x4 transpose across lane quad {p} x element {r} (verified round 3)
__device__ inline void quad_transpose(float v[4], int p) {
    float tb[4];
    #pragma unroll
    for (int q2 = 0; q2 < 4; ++q2) tb[q2] = __shfl_xor(v[q2 ^ 2], 2);
    #pragma unroll
    for (int q2 = 0; q2 < 4; ++q2) v[q2] = (((q2 ^ p) & 2) ? tb[q2] : v[q2]);
    #pragma unroll
    for (int q2 = 0; q2 < 4; ++q2) tb[q2] = __shfl_xor(v[q2 ^ 1], 1);
    #pragma unroll
    for (int q2 = 0; q2 < 4; ++q2) v[q2] = (((q2 ^ p) & 1) ? tb[q2] : v[q2]);
}

__device__ inline float lstm_cell(const float v[4], float& c) {
    float i_ = 1.f / (1.f + __expf(-v[0]));
    float f_ = 1.f / (1.f + __expf(-v[1]));
    float e2 = __expf(2.f * v[2]);
    float g_ = 1.f - 2.f / (e2 + 1.f);
    float o_ = 1.f / (1.f + __expf(-v[3]));
    c = f_ * c + i_ * g_;
    float e2c = __expf(2.f * c);
    return o_ * (1.f - 2.f / (e2c + 1.f));
}

// ------------------------------------------------- merged weight converts
__global__ void cvt_all(const float* __restrict__ e,  const float* __restrict__ wi,
                        const float* __restrict__ wh, const float* __restrict__ wc,
                        u16* __restrict__ de,  u16* __restrict__ dwi,
                        u16* __restrict__ dwh, u16* __restrict__ dwc) {
    const int N0 = NV * NE / 8, N1 = NG * NE / 8, N2 = NG * NH / 8, N3 = NV * NH / 8;
    const int total = N0 + N1 + N2 + N3;
    for (int i = blockIdx.x * blockDim.x + threadIdx.x; i < total;
         i += gridDim.x * blockDim.x) {
        const float* s; u16* d; int j;
        if (i < N0)                { s = e;  d = de;  j = i; }
        else if (i < N0 + N1)      { s = wi; d = dwi; j = i - N0; }
        else if (i < N0 + N1 + N2) { s = wh; d = dwh; j = i - N0 - N1; }
        else                       { s = wc; d = dwc; j = i - N0 - N1 - N2; }
        const float4* s4 = (const float4*)s;
        float4 a = s4[2 * j], b = s4[2 * j + 1];
        u16x8 o;
        o[0] = f2bf(a.x); o[1] = f2bf(a.y); o[2] = f2bf(a.z); o[3] = f2bf(a.w);
        o[4] = f2bf(b.x); o[5] = f2bf(b.y); o[6] = f2bf(b.z); o[7] = f2bf(b.w);
        ((u16x8*)d)[j] = o;
    }
}

// ------------------------------------------------- K1: x_gates = x @ W_ih^T
__global__ __launch_bounds__(256) void k1_xgates(
    const u16* __restrict__ Wih, const u16* __restrict__ emb,
    const int* __restrict__ toks,
    const float* __restrict__ bih, const float* __restrict__ bhh,
    float* __restrict__ xg)
{
    __shared__ u16x8 Al8[512];   // [128][32] bf16
    __shared__ u16x8 Bl8[512];
    u16* Al = (u16*)Al8;
    u16* Bl = (u16*)Bl8;

    const int t = threadIdx.x;
    const int lane = t & 63, w = t >> 6;
    const int wm = w >> 1, wn = w & 1;
    const int gtile = blockIdx.y * 128, mtile = blockIdx.x * 128;

    const int r0 = t >> 2, r1 = r0 + 64, q = t & 3;
    const int m0 = mtile + r0, m1 = mtile + r1;
    const int tok0 = toks[(m0 & 63) * NS + (m0 >> 6)];
    const int tok1 = toks[(m1 & 63) * NS + (m1 >> 6)];

    f32x4 acc[4][4];
    for (int i = 0; i < 4; ++i)
        for (int j = 0; j < 4; ++j) acc[i][j] = {0.f, 0.f, 0.f, 0.f};

    const int kc8 = (lane >> 4) * 8;
    for (int kk = 0; kk < 8; ++kk) {
        const int k0 = kk * 32;
        *(u16x8*)&Al[t * 8]         = *(const u16x8*)&Wih[(gtile + r0) * NE + k0 + q * 8];
        *(u16x8*)&Al[(t + 256) * 8] = *(const u16x8*)&Wih[(gtile + r1) * NE + k0 + q * 8];
        *(u16x8*)&Bl[t * 8]         = *(const u16x8*)&emb[tok0 * NE + k0 + q * 8];
        *(u16x8*)&Bl[(t + 256) * 8] = *(const u16x8*)&emb[tok1 * NE + k0 + q * 8];
        __syncthreads();
        bf16x8 af[4], bf[4];
        #pragma unroll
        for (int i = 0; i < 4; ++i) {
            af[i] = ld_frag(&Al[(wm * 64 + i * 16 + (lane & 15)) * 32 + kc8]);
            bf[i] = ld_frag(&Bl[(wn * 64 + i * 16 + (lane & 15)) * 32 + kc8]);
        }
        #pragma unroll
        for (int fi = 0; fi < 4; ++fi)
            #pragma unroll
            for (int fj = 0; fj < 4; ++fj)
                acc[fi][fj] = __builtin_amdgcn_mfma_f32_16x16x32_bf16(
                    af[fi], bf[fj], acc[fi][fj], 0, 0, 0);
        __syncthreads();
    }

    #pragma unroll
    for (int fi = 0; fi < 4; ++fi) {
        const int g0 = gtile + wm * 64 + fi * 16 + ((lane >> 4) << 2);
        const float4 v1 = *(const float4*)&bih[g0];
        const float4 v2 = *(const float4*)&bhh[g0];
        float badd[4] = {v1.x + v2.x, v1.y + v2.y, v1.z + v2.z, v1.w + v2.w};
        #pragma unroll
        for (int fj = 0; fj < 4; ++fj) {
            const int m = mtile + wn * 64 + fj * 16 + (lane & 15);
            const int b = m & 63, s = m >> 6;
            float* dst = &xg[s * XG_SSTRIDE + b];
            #pragma unroll
            for (int r = 0; r < 4; ++r)
                dst[(g0 + r) * 64] = acc[fi][fj][r] + badd[r];
        }
    }
}

// --------------------------------------------------------- K2: LSTM (persistent)
// R10/R13 best (364us): byte-identical. 64 blocks = 8 batch-groups x 8
// unit-slices, weights register-resident, 528-stride LDS staging, 8-flag
// group rendezvous at LLC (sc0 sc1), 8 polling lanes/wave, prefetch-first,
// hidden-history after the flag. All protocol deviations tried (R5-R9, R12)
// regressed — this is the bracketed floor for the rendezvous structure.
#define LSTM_NBLK 64

__global__ __launch_bounds__(512, 2) void k2_lstm(
    const u16* __restrict__ Whh,     // [2048][512] bf16
    const float* __restrict__ xg,    // [S][G][B]
    u16* __restrict__ hbuf,          // [2][64][512] bf16 (zeroed)
    u16* __restrict__ hidden,        // [8192][512] bf16
    u32* __restrict__ flags)         // [64] on 128B-strided lines (zeroed)
{
    __shared__ __align__(16) u16 hl[16 * 528];   // [16 rows][512+16 pad] bf16

    const int t = threadIdx.x, lane = t & 63, w = t >> 6;   // 8 waves
    const int bg = blockIdx.x >> 3, ug = blockIdx.x & 7;
    const int j = lane & 15;
    const int kc8 = (lane >> 4) * 8;

    const int ubase = ug * 64 + w * 8;
    const int grow0 = (j & 3) * 512 + ubase + (j >> 2);
    const int grow1 = grow0 + 4;

    bf16x8 bw0[16], bw1[16];
    #pragma unroll
    for (int kk = 0; kk < 16; ++kk) {
        bw0[kk] = ld_frag(&Whh[grow0 * NH + kk * 32 + kc8]);
        bw1[kk] = ld_frag(&Whh[grow1 * NH + kk * 32 + kc8]);
    }
    #pragma unroll
    for (int kk = 0; kk < 16; ++kk) {     // pin weights (one-time)
        f32x4 w0 = __builtin_bit_cast(f32x4, bw0[kk]);
        f32x4 w1 = __builtin_bit_cast(f32x4, bw1[kk]);
        asm volatile("" : "+v"(w0), "+v"(w1));
        bw0[kk] = __builtin_bit_cast(bf16x8, w0);
        bw1[kk] = __builtin_bit_cast(bf16x8, w1);
    }

    {
        u16x8 z = {0, 0, 0, 0, 0, 0, 0, 0};
        *(u16x8*)&hl[(8 + (t >> 6)) * 528 + (t & 63) * 8] = z;
    }

    const int srow = t >> 6, scol = (t & 63) * 8;
    const int soff = (bg * 8 + srow) * NH + scol;
    u16* hl_w = &hl[srow * 528 + scol];

    const int p = lane & 3;
    const int q = (lane >> 2) & 3;
    const int batg = bg * 8 + (lane >> 4) * 4 + p;
    const int un0 = ubase + q;
    const bool act = lane < 32;
    const bool sl = act && ((lane & 4) == 0);

    const int xoff0 = grow0 * 64 + bg * 8 + (lane >> 4) * 4;
    const int xoff1 = grow1 * 64 + bg * 8 + (lane >> 4) * 4;

    f32x4 xv0 = {0, 0, 0, 0}, xv1 = {0, 0, 0, 0};
    f32x4 xn0 = {0, 0, 0, 0}, xn1 = {0, 0, 0, 0};
    if (act) {
        xv0 = *(const f32x4*)&xg[xoff0];
        xv1 = *(const f32x4*)&xg[xoff1];
    }
    float cA = 0.f, cB = 0.f;

    for (int step = 0; step < NS; ++step) {
        if (act && step + 1 < NS) {
            const float* xb = &xg[(step + 1) * XG_SSTRIDE];
            prefetch16(xn0, &xb[xoff0]);
            prefetch16(xn1, &xb[xoff1]);
        }
        if (step > 0 && lane < 8) {
            const u32* fp = &flags[(bg * 8 + lane) * 32];
            while ((int)load_llc(fp) < step) __builtin_amdgcn_s_sleep(1);
        }
        {
            f32x4 hv = load_llc16(&hbuf[(step & 1) * (NB * NH) + soff]);
            *(f32x4*)hl_w = hv;
        }
        __syncthreads();

        f32x4 a00 = {0, 0, 0, 0}, a01 = {0, 0, 0, 0};
        f32x4 a10 = {0, 0, 0, 0}, a11 = {0, 0, 0, 0};
        #pragma unroll
        for (int kk = 0; kk < 16; ++kk) {
            bf16x8 av = *(const bf16x8*)&hl[j * 528 + kk * 32 + kc8];
            if (kk & 1) {
                a01 = __builtin_amdgcn_mfma_f32_16x16x32_bf16(av, bw0[kk], a01, 0, 0, 0);
                a11 = __builtin_amdgcn_mfma_f32_16x16x32_bf16(av, bw1[kk], a11, 0, 0, 0);
            } else {
                a00 = __builtin_amdgcn_mfma_f32_16x16x32_bf16(av, bw0[kk], a00, 0, 0, 0);
                a10 = __builtin_amdgcn_mfma_f32_16x16x32_bf16(av, bw1[kk], a10, 0, 0, 0);
            }
        }

        float v0[4], v1[4];
        #pragma unroll
        for (int r = 0; r < 4; ++r) {
            v0[r] = a00[r] + a01[r] + xv0[r];
            v1[r] = a10[r] + a11[r] + xv1[r];
        }
        quad_transpose(v0, p);
        quad_transpose(v1, p);

        float h0 = lstm_cell(v0, cA);
        float h1 = lstm_cell(v1, cB);
        u32 hb0 = f2bf(h0), hb1 = f2bf(h1);
        u32 o0 = (u32)__shfl_xor((int)hb0, 4);
        u32 o1 = (u32)__shfl_xor((int)hb1, 4);
        u32 pr0 = hb0 | (o0 << 16);
        u32 pr1 = hb1 | (o1 << 16);

        if (sl) {
            u16* hn = hbuf + ((step & 1) ^ 1) * (NB * NH);
            store_llc((u32*)&hn[batg * NH + un0], pr0);
            store_llc((u32*)&hn[batg * NH + un0 + 4], pr1);
        }
        xv0 = xn0; xv1 = xn1;
        __syncthreads();

        if (step + 1 < NS && t == 0)
            store_llc(&flags[blockIdx.x * 32], (u32)(step + 1));

        if (sl) {
            *(u32*)&hidden[(batg * NS + step) * NH + un0] = pr0;
            *(u32*)&hidden[(batg * NS + step) * NH + un0 + 4] = pr1;
        }
    }
}

// ------------------------------------- K3: logits = hidden @ W_cls^T + b_cls
// mfma(A=hid, B=Wc) with coalesced stores (R11) + THIS ROUND: 2-phase
// double-buffered staging (T3-minimum): STAGE(k+1) into alternate buffer
// BEFORE computing tile k; single vmcnt(0)+barrier per iteration. Stage
// latency hides under ds_read+MFMA; barriers 32 -> 16.
template <bool PACK16>
__global__ __launch_bounds__(256) void k3_cls(
    const u16* __restrict__ Wc, const u16* __restrict__ hid,
    const float* __restrict__ bcls,
    float* __restrict__ outf, u16* __restrict__ outb,
    float* __restrict__ lse)
{
    __shared__ __align__(16) u16 Al[2][128 * 32];   // Wc tiles (v rows), dbuf
    __shared__ __align__(16) u16 Bl[2][128 * 32];   // hid tiles (m rows), dbuf
    __shared__ float red[2][128];

    const int t = threadIdx.x;
    const int lane = t & 63, w = t >> 6;
    const int wm = w >> 1, wn = w & 1;
    const int vtile = blockIdx.y * 128, mtile = blockIdx.x * 128;

    const int srow = w * 16 + (lane >> 2);
    const int scol = (lane & 3) * 8;
    const u16* gA = &Wc[(vtile + srow) * NH + scol];
    const u16* gB = &hid[(mtile + srow) * NH + scol];
    const int lo0 = (w * 16) * 32;        // wave-uniform LDS row-block offsets
    const int lo1 = (w * 16 + 64) * 32;

    f32x4 acc[4][4];
    for (int i = 0; i < 4; ++i)
        for (int j2 = 0; j2 < 4; ++j2) acc[i][j2] = {0.f, 0.f, 0.f, 0.f};

    const int kc8 = (lane >> 4) * 8;

    // prologue: stage tile 0 into buffer 0
    {
        gload_lds16(gA,           &Al[0][lo0]);
        gload_lds16(gA + 64 * NH, &Al[0][lo1]);
        gload_lds16(gB,           &Bl[0][lo0]);
        gload_lds16(gB + 64 * NH, &Bl[0][lo1]);
        asm volatile("s_waitcnt vmcnt(0)" ::: "memory");
        __syncthreads();
    }

    int cur = 0;
    for (int kk = 0; kk < 16; ++kk) {
        // stage tile kk+1 into the alternate buffer (latency hides under MFMA)
        if (kk + 1 < 16) {
            const int k0 = (kk + 1) * 32;
            gload_lds16(gA + k0,           &Al[cur ^ 1][lo0]);
            gload_lds16(gA + 64 * NH + k0, &Al[cur ^ 1][lo1]);
            gload_lds16(gB + k0,           &Bl[cur ^ 1][lo0]);
            gload_lds16(gB + 64 * NH + k0, &Bl[cur ^ 1][lo1]);
        }
        bf16x8 mf[4], vf[4];
        #pragma unroll
        for (int i = 0; i < 4; ++i) {
            mf[i] = ld_frag(&Bl[cur][(wm * 64 + i * 16 + (lane & 15)) * 32 + kc8]);
            vf[i] = ld_frag(&Al[cur][(wn * 64 + i * 16 + (lane & 15)) * 32 + kc8]);
        }
        #pragma unroll
        for (int fi = 0; fi < 4; ++fi)
            #pragma unroll
            for (int fj = 0; fj < 4; ++fj)
                acc[fi][fj] = __builtin_amdgcn_mfma_f32_16x16x32_bf16(
                    mf[fi], vf[fj], acc[fi][fj], 0, 0, 0);
        // single fence per iter: drains the in-flight stage (overlapped) and
        // protects buf[cur] (overwritten at kk+2, after everyone passes here)
        asm volatile("s_waitcnt vmcnt(0)" ::: "memory");
        __syncthreads();
        cur ^= 1;
    }

    float lsum[4][4];
    #pragma unroll
    for (int fi = 0; fi < 4; ++fi)
        #pragma unroll
        for (int r = 0; r < 4; ++r) lsum[fi][r] = 0.f;

    #pragma unroll
    for (int fj = 0; fj < 4; ++fj) {
        const int v = vtile + wn * 64 + fj * 16 + (lane & 15);
        const bool vok = (v < NV);
        const float bc = vok ? bcls[v] : 0.f;
        #pragma unroll
        for (int fi = 0; fi < 4; ++fi) {
            const int m = mtile + wm * 64 + fi * 16 + ((lane >> 4) << 2);
            const int b = m >> 7, s = m & 127;
            float lg[4];
            #pragma unroll
            for (int r = 0; r < 4; ++r) {
                lg[r] = acc[fi][fj][r] + bc;
                if (vok) lsum[fi][r] += __expf(lg[r]);
            }
            if (vok) {
                if (PACK16) {
                    u16x4 o = {f2bf(lg[0]), f2bf(lg[1]), f2bf(lg[2]), f2bf(lg[3])};
                    *(u16x4*)&outb[b * OUT_BSTRIDE + v * NS + s] = o;
                } else {
                    float4 o = {lg[0], lg[1], lg[2], lg[3]};
                    *(float4*)&outf[b * OUT_BSTRIDE + v * NS + s] = o;
                }
            }
        }
    }

    #pragma unroll
    for (int fi = 0; fi < 4; ++fi)
        #pragma unroll
        for (int r = 0; r < 4; ++r) {
            float sv = lsum[fi][r];
            sv += __shfl_xor(sv, 1);
            sv += __shfl_xor(sv, 2);
            sv += __shfl_xor(sv, 4);
            sv += __shfl_xor(sv, 8);
            lsum[fi][r] = sv;
        }
    if ((lane & 15) == 0) {
        #pragma unroll
        for (int fi = 0; fi < 4; ++fi)
            #pragma unroll
            for (int r = 0; r < 4; ++r)
                red[wn][wm * 64 + fi * 16 + ((lane >> 4) << 2) + r] = lsum[fi][r];
    }
    __syncthreads();
    if (t < 128) {
        const int m = mtile + t;
        atomicAdd(&lse[m], red[0][t] + red[1][t]);
    }
}

// ------------------------------------------------------------- K4/K5 epilogue
__global__ void k4_log(const float* __restrict__ lse, float* __restrict__ ll) {
    int i = blockIdx.x * 256 + threadIdx.x;
    if (i < NBS) ll[i] = logf(lse[i]);
}

// in-place f32 path (fallback)
__global__ void k5_norm(float* __restrict__ out, const float* __restrict__ ll) {
    const int total4 = NB * NV * NS / 4;   // 16,384,000
    float4* o4 = (float4*)out;
    for (int i = blockIdx.x * blockDim.x + threadIdx.x; i < total4;
         i += gridDim.x * blockDim.x) {
        const int i4 = i * 4;
        const int b = i4 / OUT_BSTRIDE;
        const int s = i4 & 127;
        float4 v = o4[i];
        const float4 l = *(const float4*)&ll[b * NS + s];
        v.x -= l.x; v.y -= l.y; v.z -= l.z; v.w -= l.w;
        o4[i] = v;
    }
}

// bf16-logits path: read u16x4 from ws, write f32 out
__global__ void k5_bf16(float* __restrict__ out, const u16* __restrict__ lgb,
                        const float* __restrict__ ll) {
    const int total4 = NB * NV * NS / 4;
    float4* o4 = (float4*)out;
    const u16x4* l4 = (const u16x4*)lgb;
    for (int i = blockIdx.x * blockDim.x + threadIdx.x; i < total4;
         i += gridDim.x * blockDim.x) {
        const int i4 = i * 4;
        const int b = i4 / OUT_BSTRIDE;
        const int s = i4 & 127;
        u16x4 g = l4[i];
        const float4 l = *(const float4*)&ll[b * NS + s];
        float4 v;
        v.x = bf2f(g[0]) - l.x;
        v.y = bf2f(g[1]) - l.y;
        v.z = bf2f(g[2]) - l.z;
        v.w = bf2f(g[3]) - l.w;
        o4[i] = v;
    }
}

// ---------------------------------------------------------------------------
extern "C" void kernel_launch(void* const* d_in, const int* in_sizes, int n_in,
                              void* d_out, int out_size, void* d_ws, size_t ws_size,
                              hipStream_t stream) {
    const int*   toks   = (const int*)d_in[0];
    const float* emb_f  = (const float*)d_in[1];
    const float* Wih_f  = (const float*)d_in[2];
    const float* Whh_f  = (const float*)d_in[3];
    const float* bih    = (const float*)d_in[4];
    const float* bhh    = (const float*)d_in[5];
    const float* Wcls_f = (const float*)d_in[6];
    const float* bcls   = (const float*)d_in[7];
    float* out = (float*)d_out;
    char*  ws  = (char*)d_ws;

    // workspace layout (bytes)
    u32*   flags  = (u32*)(ws + 0);            // 8192 (64 x 128B lines)
    float* lse    = (float*)(ws + 8192);       // 32768
    float* loglse = (float*)(ws + 40960);      // 32768
    u16*   hbuf   = (u16*)(ws + 73728);        // 131072 (zeroed: h0 = 0)
    u16*   embb   = (u16*)(ws + 204800);       // 4,096,000
    u16*   wihb   = (u16*)(ws + 4300800);      // 1,048,576
    u16*   whhb   = (u16*)(ws + 5349376);      // 2,097,152
    u16*   wclsb  = (u16*)(ws + 7446528);      // 8,388,608 (padded 8192 rows)
    u16*   hidden = (u16*)(ws + 15835136);     // 8,388,608
    u16*   lgb    = (u16*)(ws + 24223744);     // 131,072,000 (bf16 logits, optional)
    const bool bigws = ws_size >= (size_t)24223744 + (size_t)NB * NV * NS * 2;

    // x_gates f32 [S][G][B] lives in d_out scratch (16.8M floats < 65.5M)
    float* xg = out;

    hipMemsetAsync(ws, 0, 204800, stream);     // flags + lse + loglse + hbuf
    hipMemsetAsync((char*)wclsb + NV * NH * 2, 0, (NVP - NV) * NH * 2, stream);

    cvt_all<<<2048, 256, 0, stream>>>(emb_f, Wih_f, Whh_f, Wcls_f,
                                      embb, wihb, whhb, wclsb);

    k1_xgates<<<dim3(64, 16), 256, 0, stream>>>(wihb, embb, toks, bih, bhh, xg);
    k2_lstm<<<LSTM_NBLK, 512, 0, stream>>>(whhb, xg, hbuf, hidden, flags);
    if (bigws) {
        k3_cls<true><<<dim3(64, 64), 256, 0, stream>>>(wclsb, hidden, bcls,
                                                       out, lgb, lse);
        k4_log<<<32, 256, 0, stream>>>(lse, loglse);
        k5_bf16<<<2048, 256, 0, stream>>>(out, lgb, loglse);
    } else {
        k3_cls<false><<<dim3(64, 64), 256, 0, stream>>>(wclsb, hidden, bcls,
                                                        out, lgb, lse);
        k4_log<<<32, 256, 0, stream>>>(lse, loglse);
        k5_norm<<<2048, 256, 0, stream>>>(out, loglse);
    }
}